// Round 6
// baseline (463.427 us; speedup 1.0000x reference)
//
#include <hip/hip_runtime.h>
#include <hip/hip_bf16.h>

// Problem constants
#define BB 8
#define EE 16
#define NN 262144          // H*W = 512*512
#define KK 32
#define DELTA_VAR 0.5f
#define TWO_DELTA_DIST 3.0f
#define GAMMA_REG 0.001f

#define P1 1024            // pixels per block, kernel 1
#define TILE 256           // pixels per block, kernel 2

// ---------------------------------------------------------------------------
// Kernel 1: per-(b,k) pixel counts and per-(b,k,e) embedding sums.
// Fire-and-forget LDS atomics (ds_add_f32, no return -> no RMW latency chain).
// hist[e*33+k]: pad 33 -> bank (e+k)%32 spreads the 4 e-groups of a wave.
// LDS = 2.2 KB -> 8 blocks/CU resident (32 waves/CU) for latency hiding.
// ---------------------------------------------------------------------------
__global__ __launch_bounds__(256) void k1_sums(const float* __restrict__ emb,
                                               const int* __restrict__ mask,
                                               float* __restrict__ g_sums,
                                               float* __restrict__ g_cnt) {
    __shared__ float hist[EE * 33];
    __shared__ float chist[KK];
    const int t = threadIdx.x;
    const int b = blockIdx.y;
    const int e = t >> 4, sub = t & 15;

    for (int i = t; i < EE * 33; i += 256) hist[i] = 0.0f;
    if (t < KK) chist[t] = 0.0f;
    __syncthreads();

    const int n0 = blockIdx.x * P1;
    const float4* ep = (const float4*)(emb + ((size_t)b * EE + e) * NN + n0);
    const int4*   mp = (const int4*)(mask + (size_t)b * NN + n0);
    float* hrow = &hist[e * 33];

    for (int i = 0; i < P1 / 64; i++) {
        float4 v  = ep[i * 16 + sub];
        int4   l4 = mp[i * 16 + sub];
        int   ks[4] = {l4.x, l4.y, l4.z, l4.w};
        float vs[4] = {v.x, v.y, v.z, v.w};
        #pragma unroll
        for (int j = 0; j < 4; j++) {
            int k = ks[j];
            if (k > 0) {
                atomicAdd(&hrow[k - 1], vs[j]);          // ds_add_f32, no return
                if (e == 0) atomicAdd(&chist[k - 1], 1.0f);
            }
        }
    }
    __syncthreads();

    // flush 512 partial sums + 32 counts to global
    for (int idx = t; idx < KK * EE; idx += 256) {
        int ee = idx >> 5, k = idx & 31;
        atomicAdd(&g_sums[((size_t)b * KK + k) * EE + ee], hist[ee * 33 + k]);
    }
    if (t < KK) atomicAdd(&g_cnt[b * KK + t], chist[t]);
}

// ---------------------------------------------------------------------------
// Kernel 2: variance-term accumulation. One 256-pixel tile per block;
// 4 coalesced float4 stages per thread; each thread owns one pixel.
// Centers padded x17: for fixed e, 17k mod 32 is bijective -> distinct labels
// hit distinct banks, equal labels broadcast -> conflict-free.
// LDS ~20 KB -> 8 blocks/CU.
// ---------------------------------------------------------------------------
__global__ __launch_bounds__(256) void k2_var(const float* __restrict__ emb,
                                              const int* __restrict__ mask,
                                              const float* __restrict__ g_sums,
                                              const float* __restrict__ g_cnt,
                                              float* __restrict__ g_var) {
    __shared__ float tile[EE][TILE];
    __shared__ float c_lds[KK * 17];
    __shared__ int   lab[TILE];
    __shared__ float whist[4][KK];
    const int t = threadIdx.x;
    const int b = blockIdx.y;
    const int n0 = blockIdx.x * TILE;

    // centers for this batch
    for (int idx = t; idx < KK * EE; idx += 256) {
        int k = idx >> 4, e = idx & 15;
        float cnt = g_cnt[b * KK + k];
        c_lds[k * 17 + e] = g_sums[((size_t)b * KK + k) * EE + e] / fmaxf(cnt, 1.0f);
    }
    if (t < 4 * KK) ((float*)whist)[t] = 0.0f;

    // stage tile: 16 rows x 256 floats = 1024 float4, 4 per thread (coalesced)
    const float4* ef = (const float4*)(emb + (size_t)b * EE * NN);
    #pragma unroll
    for (int r = 0; r < 4; r++) {
        int idx = r * 256 + t;
        int e = idx >> 6;          // TILE/4 = 64 float4 per row
        int off = idx & 63;
        float4 v = ef[(size_t)e * (NN / 4) + (n0 / 4) + off];
        *((float4*)&tile[e][off * 4]) = v;
    }
    if (t < TILE / 4) {
        ((int4*)lab)[t] = ((const int4*)(mask + (size_t)b * NN + n0))[t];
    }
    __syncthreads();

    int k = lab[t];
    if (k > 0) {
        int kk = k - 1;
        float sq = 0.0f;
        #pragma unroll
        for (int e = 0; e < EE; e++) {
            float d = tile[e][t] - c_lds[kk * 17 + e];
            sq += d * d;
        }
        float dd = sqrtf(sq);
        float h = fmaxf(dd - DELTA_VAR, 0.0f);
        atomicAdd(&whist[t >> 6][kk], h * h);
    }
    __syncthreads();

    if (t < KK) {
        float s = whist[0][t] + whist[1][t] + whist[2][t] + whist[3][t];
        atomicAdd(&g_var[b * KK + t], s);
    }
}

// ---------------------------------------------------------------------------
// Kernel 3: finalize. One block, thread (b = t>>5, k = t&31).
// ---------------------------------------------------------------------------
__global__ __launch_bounds__(256) void k3_final(const float* __restrict__ g_sums,
                                                const float* __restrict__ g_cnt,
                                                const float* __restrict__ g_var,
                                                float* __restrict__ out) {
    __shared__ float cen[BB][KK][EE];
    __shared__ float pres[BB][KK];
    __shared__ float red[BB][4];
    const int t = threadIdx.x;
    const int b = t >> 5, k = t & 31;

    float cnt = g_cnt[b * KK + k];
    float sc = fmaxf(cnt, 1.0f);
    float c2 = 0.0f;
    #pragma unroll
    for (int e = 0; e < EE; e++) {
        float c = g_sums[((size_t)b * KK + k) * EE + e] / sc;
        cen[b][k][e] = c;
        c2 += c * c;
    }
    float presf = (cnt > 0.0f) ? 1.0f : 0.0f;
    pres[b][k] = presf;
    float per_inst = g_var[b * KK + k] / sc;
    float cn = presf * sqrtf(c2);
    __syncthreads();

    float hp = 0.0f;
    if (presf > 0.0f) {
        for (int j = k + 1; j < KK; j++) {
            if (pres[b][j] > 0.0f) {
                float dsq = 0.0f;
                #pragma unroll
                for (int e = 0; e < EE; e++) {
                    float d = cen[b][k][e] - cen[b][j][e];
                    dsq += d * d;
                }
                float dd = sqrtf(dsq);
                float h = fmaxf(TWO_DELTA_DIST - dd, 0.0f);
                hp += h * h;
            }
        }
    }

    // reduce across the 32 k-lanes of each batch (width-32 subgroups align
    // with the b = t>>5 partition on wave64)
    float v0 = per_inst, v1 = hp, v2 = cn, v3 = presf;
    #pragma unroll
    for (int off = 16; off > 0; off >>= 1) {
        v0 += __shfl_down(v0, off, 32);
        v1 += __shfl_down(v1, off, 32);
        v2 += __shfl_down(v2, off, 32);
        v3 += __shfl_down(v3, off, 32);
    }
    if (k == 0) {
        float n_inst = v3;
        float validf = (n_inst > 0.0f) ? 1.0f : 0.0f;
        float safe_n = fmaxf(n_inst, 1.0f);
        float lv = v0 / safe_n;
        float npairs = n_inst * (n_inst - 1.0f) * 0.5f;
        float ld = v1 / fmaxf(npairs, 1.0f);
        float lr = v2 / safe_n;
        red[b][0] = lv * validf;
        red[b][1] = ld * validf;
        red[b][2] = lr * validf;
        red[b][3] = validf;
    }
    __syncthreads();
    if (t == 0) {
        float sv = 0, sd = 0, sr = 0, vb = 0;
        for (int b2 = 0; b2 < BB; b2++) {
            sv += red[b2][0]; sd += red[b2][1]; sr += red[b2][2]; vb += red[b2][3];
        }
        vb = fmaxf(vb, 1.0f);
        float L_var = sv / vb, L_dist = sd / vb, L_reg = sr / vb;
        out[0] = L_var + L_dist + GAMMA_REG * L_reg;
        out[1] = L_var;
        out[2] = L_dist;
        out[3] = L_reg;
    }
}

extern "C" void kernel_launch(void* const* d_in, const int* in_sizes, int n_in,
                              void* d_out, int out_size, void* d_ws, size_t ws_size,
                              hipStream_t stream) {
    const float* emb  = (const float*)d_in[0];
    const int*   mask = (const int*)d_in[1];
    float* out = (float*)d_out;
    float* ws  = (float*)d_ws;

    float* g_sums = ws;                 // B*K*E = 4096 floats
    float* g_cnt  = ws + BB * KK * EE;  // 256 floats
    float* g_var  = g_cnt + BB * KK;    // 256 floats

    hipMemsetAsync(d_ws, 0, (BB * KK * EE + 2 * BB * KK) * sizeof(float), stream);

    dim3 blk(256);
    dim3 g1(NN / P1, BB);               // (256, 8)
    k1_sums<<<g1, blk, 0, stream>>>(emb, mask, g_sums, g_cnt);

    dim3 g2(NN / TILE, BB);             // (1024, 8)
    k2_var<<<g2, blk, 0, stream>>>(emb, mask, g_sums, g_cnt, g_var);

    k3_final<<<dim3(1), blk, 0, stream>>>(g_sums, g_cnt, g_var, out);
}

// Round 11
// 288.104 us; speedup vs baseline: 1.6085x; 1.6085x over previous
//
#include <hip/hip_runtime.h>
#include <hip/hip_bf16.h>

// Problem constants
#define BB 8
#define EE 16
#define NN 262144          // H*W = 512*512
#define KK 32
#define DELTA_VAR 0.5f
#define TWO_DELTA_DIST 3.0f
#define GAMMA_REG 0.001f

#define P1 1024            // pixels per block, kernel 1
#define P3 1024            // pixels per block, kernel 3

#define SCALE_S 262144.0f  // 2^18 fixed-point scale for embedding sums
#define SCALE_V 1024.0f    // 2^10 fixed-point scale for hinged^2 sums

// ws layout (bytes):
//   q_sums : long long [BB][KK][EE]   @ 0      (32768 B)  -- atomic i64
//   q_cnt  : unsigned  [BB][KK]       @ 32768  (1024 B)   -- atomic u32
//   q_var  : unsigned long long[BB][KK] @ 33792 (2048 B)  -- atomic u64
//   g_cen  : float [BB][KK][EE]       @ 35840  (16384 B)  -- plain stores
//   g_cntf : float [BB][KK]           @ 52224  (1024 B)   -- plain stores

// ---------------------------------------------------------------------------
// Kernel 1: per-(b,k) counts and per-(b,k,e) quantized embedding sums.
// ALL atomics are integer (native fire-and-forget ds_add_u32 /
// global_atomic_add_x2) -- no float CAS loops anywhere.
// ---------------------------------------------------------------------------
__global__ __launch_bounds__(256) void k1_sums(const float* __restrict__ emb,
                                               const int* __restrict__ mask,
                                               unsigned long long* __restrict__ q_sums,
                                               unsigned int* __restrict__ q_cnt) {
    __shared__ int hist[EE * 33];       // pad 33: bank (e+k)%32
    __shared__ unsigned int chist[KK];
    const int t = threadIdx.x;
    const int b = blockIdx.y;
    const int e = t >> 4, sub = t & 15;

    for (int i = t; i < EE * 33; i += 256) hist[i] = 0;
    if (t < KK) chist[t] = 0u;
    __syncthreads();

    const int n0 = blockIdx.x * P1;
    const float4* ep = (const float4*)(emb + ((size_t)b * EE + e) * NN + n0);
    const int4*   mp = (const int4*)(mask + (size_t)b * NN + n0);
    int* hrow = &hist[e * 33];

    for (int i = 0; i < P1 / 64; i++) {
        float4 v  = ep[i * 16 + sub];
        int4   l4 = mp[i * 16 + sub];
        int   ks[4] = {l4.x, l4.y, l4.z, l4.w};
        float vs[4] = {v.x, v.y, v.z, v.w};
        #pragma unroll
        for (int j = 0; j < 4; j++) {
            int k = ks[j];
            if (k > 0) {
                int q = (int)rintf(vs[j] * SCALE_S);
                atomicAdd(&hrow[k - 1], q);              // ds_add_u32, native
                if (e == 0) atomicAdd(&chist[k - 1], 1u);
            }
        }
    }
    __syncthreads();

    // flush 512 partial sums (i64 atomic, two's-complement) + 32 counts
    for (int idx = t; idx < KK * EE; idx += 256) {
        int ee = idx >> 5, k = idx & 31;
        long long val = (long long)hist[ee * 33 + k];
        atomicAdd(&q_sums[((size_t)b * KK + k) * EE + ee],
                  (unsigned long long)val);              // global_atomic_add_x2
    }
    if (t < KK) atomicAdd(&q_cnt[b * KK + t], chist[t]);
}

// ---------------------------------------------------------------------------
// Kernel 2: dequantize -> float centers + float counts (plain stores).
// One block, 256 threads, 16 center values each.
// ---------------------------------------------------------------------------
__global__ __launch_bounds__(256) void k2_centers(const unsigned long long* __restrict__ q_sums,
                                                  const unsigned int* __restrict__ q_cnt,
                                                  float* __restrict__ g_cen,
                                                  float* __restrict__ g_cntf) {
    const int t = threadIdx.x;
    for (int idx = t; idx < BB * KK * EE; idx += 256) {
        int bk = idx >> 4;                    // b*KK + k
        float cnt = (float)q_cnt[bk];
        float s = (float)(long long)q_sums[idx] * (1.0f / SCALE_S);
        g_cen[idx] = s / fmaxf(cnt, 1.0f);
    }
    for (int bk = t; bk < BB * KK; bk += 256) g_cntf[bk] = (float)q_cnt[bk];
}

// ---------------------------------------------------------------------------
// Kernel 3: variance-term accumulation. Direct coalesced float4 global loads
// (4 pixels x 16 e in registers); centers staged in LDS (x17 padding: 17k
// mod 32 bijective -> distinct labels distinct banks, equal labels
// broadcast). u32 LDS hist -> u64 global atomic. No float atomics.
// ---------------------------------------------------------------------------
__global__ __launch_bounds__(256) void k3_var(const float* __restrict__ emb,
                                              const int* __restrict__ mask,
                                              const float* __restrict__ g_cen,
                                              unsigned long long* __restrict__ q_var) {
    __shared__ float c_lds[KK * 17];
    __shared__ unsigned int vhist[KK];
    const int t = threadIdx.x;
    const int b = blockIdx.y;
    const int n0 = blockIdx.x * P3;

    for (int idx = t; idx < KK * EE; idx += 256) {
        int k = idx >> 4, e = idx & 15;
        c_lds[k * 17 + e] = g_cen[idx + (size_t)b * KK * EE];
    }
    if (t < KK) vhist[t] = 0u;
    __syncthreads();

    // 4 pixels per thread: lane-consecutive float4 -> fully coalesced
    const float4* ef = (const float4*)(emb + (size_t)b * EE * NN);
    const int fidx = (n0 >> 2) + t;
    float4 x[EE];
    #pragma unroll
    for (int e = 0; e < EE; e++) x[e] = ef[(size_t)e * (NN / 4) + fidx];
    int4 l4 = ((const int4*)(mask + (size_t)b * NN + n0))[t];
    int ks[4] = {l4.x, l4.y, l4.z, l4.w};

    #pragma unroll
    for (int j = 0; j < 4; j++) {
        int k = ks[j];
        if (k > 0) {
            const float* c = &c_lds[(k - 1) * 17];
            float sq = 0.0f;
            #pragma unroll
            for (int e = 0; e < EE; e++) {
                float xv = (j == 0) ? x[e].x : (j == 1) ? x[e].y : (j == 2) ? x[e].z : x[e].w;
                float d = xv - c[e];
                sq += d * d;
            }
            float dd = sqrtf(sq);
            float h = fmaxf(dd - DELTA_VAR, 0.0f);
            unsigned int q = (unsigned int)rintf(h * h * SCALE_V);
            atomicAdd(&vhist[k - 1], q);                 // ds_add_u32, native
        }
    }
    __syncthreads();

    if (t < KK) atomicAdd(&q_var[b * KK + t], (unsigned long long)vhist[t]);
}

// ---------------------------------------------------------------------------
// Kernel 4: finalize. One block, thread (b = t>>5, k = t&31).
// ---------------------------------------------------------------------------
__global__ __launch_bounds__(256) void k4_final(const float* __restrict__ g_cen,
                                                const float* __restrict__ g_cntf,
                                                const unsigned long long* __restrict__ q_var,
                                                float* __restrict__ out) {
    __shared__ float cen[BB][KK][EE];
    __shared__ float pres[BB][KK];
    __shared__ float red[BB][4];
    const int t = threadIdx.x;
    const int b = t >> 5, k = t & 31;

    float cnt = g_cntf[b * KK + k];
    float sc = fmaxf(cnt, 1.0f);
    float c2 = 0.0f;
    #pragma unroll
    for (int e = 0; e < EE; e++) {
        float c = g_cen[((size_t)b * KK + k) * EE + e];
        cen[b][k][e] = c;
        c2 += c * c;
    }
    float presf = (cnt > 0.0f) ? 1.0f : 0.0f;
    pres[b][k] = presf;
    float per_inst = (float)((double)q_var[b * KK + k] * (1.0 / SCALE_V)) / sc;
    float cn = presf * sqrtf(c2);
    __syncthreads();

    float hp = 0.0f;
    if (presf > 0.0f) {
        for (int j = k + 1; j < KK; j++) {
            if (pres[b][j] > 0.0f) {
                float dsq = 0.0f;
                #pragma unroll
                for (int e = 0; e < EE; e++) {
                    float d = cen[b][k][e] - cen[b][j][e];
                    dsq += d * d;
                }
                float dd = sqrtf(dsq);
                float h = fmaxf(TWO_DELTA_DIST - dd, 0.0f);
                hp += h * h;
            }
        }
    }

    // width-32 subgroups align with the b = t>>5 partition on wave64
    float v0 = per_inst, v1 = hp, v2 = cn, v3 = presf;
    #pragma unroll
    for (int off = 16; off > 0; off >>= 1) {
        v0 += __shfl_down(v0, off, 32);
        v1 += __shfl_down(v1, off, 32);
        v2 += __shfl_down(v2, off, 32);
        v3 += __shfl_down(v3, off, 32);
    }
    if (k == 0) {
        float n_inst = v3;
        float validf = (n_inst > 0.0f) ? 1.0f : 0.0f;
        float safe_n = fmaxf(n_inst, 1.0f);
        float lv = v0 / safe_n;
        float npairs = n_inst * (n_inst - 1.0f) * 0.5f;
        float ld = v1 / fmaxf(npairs, 1.0f);
        float lr = v2 / safe_n;
        red[b][0] = lv * validf;
        red[b][1] = ld * validf;
        red[b][2] = lr * validf;
        red[b][3] = validf;
    }
    __syncthreads();
    if (t == 0) {
        float sv = 0, sd = 0, sr = 0, vb = 0;
        for (int b2 = 0; b2 < BB; b2++) {
            sv += red[b2][0]; sd += red[b2][1]; sr += red[b2][2]; vb += red[b2][3];
        }
        vb = fmaxf(vb, 1.0f);
        float L_var = sv / vb, L_dist = sd / vb, L_reg = sr / vb;
        out[0] = L_var + L_dist + GAMMA_REG * L_reg;
        out[1] = L_var;
        out[2] = L_dist;
        out[3] = L_reg;
    }
}

extern "C" void kernel_launch(void* const* d_in, const int* in_sizes, int n_in,
                              void* d_out, int out_size, void* d_ws, size_t ws_size,
                              hipStream_t stream) {
    const float* emb  = (const float*)d_in[0];
    const int*   mask = (const int*)d_in[1];
    float* out = (float*)d_out;
    char* ws = (char*)d_ws;

    unsigned long long* q_sums = (unsigned long long*)(ws);           // 32768 B
    unsigned int*       q_cnt  = (unsigned int*)(ws + 32768);         // 1024 B
    unsigned long long* q_var  = (unsigned long long*)(ws + 33792);   // 2048 B
    float*              g_cen  = (float*)(ws + 35840);                // 16384 B
    float*              g_cntf = (float*)(ws + 52224);                // 1024 B

    hipMemsetAsync(d_ws, 0, 35840, stream);   // zero all atomic accumulators

    dim3 blk(256);
    k1_sums<<<dim3(NN / P1, BB), blk, 0, stream>>>(emb, mask, q_sums, q_cnt);
    k2_centers<<<dim3(1), blk, 0, stream>>>(q_sums, q_cnt, g_cen, g_cntf);
    k3_var<<<dim3(NN / P3, BB), blk, 0, stream>>>(emb, mask, g_cen, q_var);
    k4_final<<<dim3(1), blk, 0, stream>>>(g_cen, g_cntf, q_var, out);
}

// Round 13
// 282.100 us; speedup vs baseline: 1.6428x; 1.0213x over previous
//
#include <hip/hip_runtime.h>
#include <hip/hip_bf16.h>

// Problem constants
#define BB 8
#define EE 16
#define NN 262144          // H*W = 512*512
#define KK 32
#define DELTA_VAR 0.5f
#define TWO_DELTA_DIST 3.0f
#define GAMMA_REG 0.001f

#define P1 1024            // pixels per block, kernel 1
#define P3 1024            // pixels per block, kernel 3

#define SCALE_S 262144.0f  // 2^18 fixed-point scale for embedding sums
#define SCALE_V 1024.0f    // 2^10 fixed-point scale for hinged^2 sums

// ws layout (bytes):
//   q_sums : long long [BB][KK][EE]   @ 0      (32768 B)  -- atomic i64
//   q_cnt  : unsigned  [BB][KK]       @ 32768  (1024 B)   -- atomic u32
//   q_var  : unsigned long long[BB][KK] @ 33792 (2048 B)  -- atomic u64
//   g_cen  : float [BB][KK][EE]       @ 35840  (16384 B)  -- plain stores
//   g_cntf : float [BB][KK]           @ 52224  (1024 B)   -- plain stores

// ---------------------------------------------------------------------------
// Kernel 1: per-(b,k) counts and per-(b,k,e) quantized embedding sums.
// MLP-first structure: each thread owns 4 pixels and loads all 16 e-planes
// as 16 INDEPENDENT float4s (no loop-carried register reuse -> ~16
// outstanding global loads per wave instead of 1; the round-11 version's
// VGPR=8 allocation serialized every load). Integer LDS atomics (native
// ds_add_u32, fire-and-forget) -> u64 global flush. No float atomics.
// ---------------------------------------------------------------------------
__global__ __launch_bounds__(256) void k1_sums(const float* __restrict__ emb,
                                               const int* __restrict__ mask,
                                               unsigned long long* __restrict__ q_sums,
                                               unsigned int* __restrict__ q_cnt) {
    __shared__ int hist[EE * 33];       // pad 33: bank (e+k)%32
    __shared__ unsigned int chist[KK];
    const int t = threadIdx.x;
    const int b = blockIdx.y;

    for (int i = t; i < EE * 33; i += 256) hist[i] = 0;
    if (t < KK) chist[t] = 0u;
    __syncthreads();

    const int n0 = blockIdx.x * P1;
    const int fidx = (n0 >> 2) + t;     // this thread's float4 index (4 pixels)

    // 16 independent, fully-coalesced 1KB/wave loads -- all in flight at once
    const float4* ef = (const float4*)(emb + (size_t)b * EE * NN);
    float4 x[EE];
    #pragma unroll
    for (int e = 0; e < EE; e++) x[e] = ef[(size_t)e * (NN / 4) + fidx];
    int4 l4 = ((const int4*)(mask + (size_t)b * NN + n0))[t];
    int ks[4] = {l4.x, l4.y, l4.z, l4.w};

    #pragma unroll
    for (int j = 0; j < 4; j++) {
        int k = ks[j];
        if (k > 0) {
            int kk = k - 1;
            atomicAdd(&chist[kk], 1u);                   // one count per pixel
            #pragma unroll
            for (int e = 0; e < EE; e++) {
                float xv = (j == 0) ? x[e].x : (j == 1) ? x[e].y
                         : (j == 2) ? x[e].z : x[e].w;
                atomicAdd(&hist[e * 33 + kk], (int)rintf(xv * SCALE_S));
            }
        }
    }
    __syncthreads();

    // flush 512 partial sums (i64 atomic, two's-complement) + 32 counts
    for (int idx = t; idx < KK * EE; idx += 256) {
        int ee = idx >> 5, k = idx & 31;
        long long val = (long long)hist[ee * 33 + k];
        atomicAdd(&q_sums[((size_t)b * KK + k) * EE + ee],
                  (unsigned long long)val);              // global_atomic_add_x2
    }
    if (t < KK) atomicAdd(&q_cnt[b * KK + t], chist[t]);
}

// ---------------------------------------------------------------------------
// Kernel 2: dequantize -> float centers + float counts (plain stores).
// ---------------------------------------------------------------------------
__global__ __launch_bounds__(256) void k2_centers(const unsigned long long* __restrict__ q_sums,
                                                  const unsigned int* __restrict__ q_cnt,
                                                  float* __restrict__ g_cen,
                                                  float* __restrict__ g_cntf) {
    const int t = threadIdx.x;
    for (int idx = t; idx < BB * KK * EE; idx += 256) {
        int bk = idx >> 4;                    // b*KK + k
        float cnt = (float)q_cnt[bk];
        float s = (float)(long long)q_sums[idx] * (1.0f / SCALE_S);
        g_cen[idx] = s / fmaxf(cnt, 1.0f);
    }
    for (int bk = t; bk < BB * KK; bk += 256) g_cntf[bk] = (float)q_cnt[bk];
}

// ---------------------------------------------------------------------------
// Kernel 3: variance-term accumulation. Same MLP pattern (16 independent
// float4 loads / thread); centers staged in LDS (x17 padding: 17k mod 32
// bijective -> distinct labels distinct banks, equal labels broadcast).
// u32 LDS hist -> u64 global atomic. No float atomics.
// ---------------------------------------------------------------------------
__global__ __launch_bounds__(256) void k3_var(const float* __restrict__ emb,
                                              const int* __restrict__ mask,
                                              const float* __restrict__ g_cen,
                                              unsigned long long* __restrict__ q_var) {
    __shared__ float c_lds[KK * 17];
    __shared__ unsigned int vhist[KK];
    const int t = threadIdx.x;
    const int b = blockIdx.y;
    const int n0 = blockIdx.x * P3;

    for (int idx = t; idx < KK * EE; idx += 256) {
        int k = idx >> 4, e = idx & 15;
        c_lds[k * 17 + e] = g_cen[idx + (size_t)b * KK * EE];
    }
    if (t < KK) vhist[t] = 0u;
    __syncthreads();

    const float4* ef = (const float4*)(emb + (size_t)b * EE * NN);
    const int fidx = (n0 >> 2) + t;
    float4 x[EE];
    #pragma unroll
    for (int e = 0; e < EE; e++) x[e] = ef[(size_t)e * (NN / 4) + fidx];
    int4 l4 = ((const int4*)(mask + (size_t)b * NN + n0))[t];
    int ks[4] = {l4.x, l4.y, l4.z, l4.w};

    #pragma unroll
    for (int j = 0; j < 4; j++) {
        int k = ks[j];
        if (k > 0) {
            const float* c = &c_lds[(k - 1) * 17];
            float sq = 0.0f;
            #pragma unroll
            for (int e = 0; e < EE; e++) {
                float xv = (j == 0) ? x[e].x : (j == 1) ? x[e].y
                         : (j == 2) ? x[e].z : x[e].w;
                float d = xv - c[e];
                sq += d * d;
            }
            float dd = sqrtf(sq);
            float h = fmaxf(dd - DELTA_VAR, 0.0f);
            unsigned int q = (unsigned int)rintf(h * h * SCALE_V);
            atomicAdd(&vhist[k - 1], q);                 // ds_add_u32, native
        }
    }
    __syncthreads();

    if (t < KK) atomicAdd(&q_var[b * KK + t], (unsigned long long)vhist[t]);
}

// ---------------------------------------------------------------------------
// Kernel 4: finalize. One block, thread (b = t>>5, k = t&31).
// ---------------------------------------------------------------------------
__global__ __launch_bounds__(256) void k4_final(const float* __restrict__ g_cen,
                                                const float* __restrict__ g_cntf,
                                                const unsigned long long* __restrict__ q_var,
                                                float* __restrict__ out) {
    __shared__ float cen[BB][KK][EE];
    __shared__ float pres[BB][KK];
    __shared__ float red[BB][4];
    const int t = threadIdx.x;
    const int b = t >> 5, k = t & 31;

    float cnt = g_cntf[b * KK + k];
    float sc = fmaxf(cnt, 1.0f);
    float c2 = 0.0f;
    #pragma unroll
    for (int e = 0; e < EE; e++) {
        float c = g_cen[((size_t)b * KK + k) * EE + e];
        cen[b][k][e] = c;
        c2 += c * c;
    }
    float presf = (cnt > 0.0f) ? 1.0f : 0.0f;
    pres[b][k] = presf;
    float per_inst = (float)((double)q_var[b * KK + k] * (1.0 / SCALE_V)) / sc;
    float cn = presf * sqrtf(c2);
    __syncthreads();

    float hp = 0.0f;
    if (presf > 0.0f) {
        for (int j = k + 1; j < KK; j++) {
            if (pres[b][j] > 0.0f) {
                float dsq = 0.0f;
                #pragma unroll
                for (int e = 0; e < EE; e++) {
                    float d = cen[b][k][e] - cen[b][j][e];
                    dsq += d * d;
                }
                float dd = sqrtf(dsq);
                float h = fmaxf(TWO_DELTA_DIST - dd, 0.0f);
                hp += h * h;
            }
        }
    }

    // width-32 subgroups align with the b = t>>5 partition on wave64
    float v0 = per_inst, v1 = hp, v2 = cn, v3 = presf;
    #pragma unroll
    for (int off = 16; off > 0; off >>= 1) {
        v0 += __shfl_down(v0, off, 32);
        v1 += __shfl_down(v1, off, 32);
        v2 += __shfl_down(v2, off, 32);
        v3 += __shfl_down(v3, off, 32);
    }
    if (k == 0) {
        float n_inst = v3;
        float validf = (n_inst > 0.0f) ? 1.0f : 0.0f;
        float safe_n = fmaxf(n_inst, 1.0f);
        float lv = v0 / safe_n;
        float npairs = n_inst * (n_inst - 1.0f) * 0.5f;
        float ld = v1 / fmaxf(npairs, 1.0f);
        float lr = v2 / safe_n;
        red[b][0] = lv * validf;
        red[b][1] = ld * validf;
        red[b][2] = lr * validf;
        red[b][3] = validf;
    }
    __syncthreads();
    if (t == 0) {
        float sv = 0, sd = 0, sr = 0, vb = 0;
        for (int b2 = 0; b2 < BB; b2++) {
            sv += red[b2][0]; sd += red[b2][1]; sr += red[b2][2]; vb += red[b2][3];
        }
        vb = fmaxf(vb, 1.0f);
        float L_var = sv / vb, L_dist = sd / vb, L_reg = sr / vb;
        out[0] = L_var + L_dist + GAMMA_REG * L_reg;
        out[1] = L_var;
        out[2] = L_dist;
        out[3] = L_reg;
    }
}

extern "C" void kernel_launch(void* const* d_in, const int* in_sizes, int n_in,
                              void* d_out, int out_size, void* d_ws, size_t ws_size,
                              hipStream_t stream) {
    const float* emb  = (const float*)d_in[0];
    const int*   mask = (const int*)d_in[1];
    float* out = (float*)d_out;
    char* ws = (char*)d_ws;

    unsigned long long* q_sums = (unsigned long long*)(ws);           // 32768 B
    unsigned int*       q_cnt  = (unsigned int*)(ws + 32768);         // 1024 B
    unsigned long long* q_var  = (unsigned long long*)(ws + 33792);   // 2048 B
    float*              g_cen  = (float*)(ws + 35840);                // 16384 B
    float*              g_cntf = (float*)(ws + 52224);                // 1024 B

    hipMemsetAsync(d_ws, 0, 35840, stream);   // zero all atomic accumulators

    dim3 blk(256);
    k1_sums<<<dim3(NN / P1, BB), blk, 0, stream>>>(emb, mask, q_sums, q_cnt);
    k2_centers<<<dim3(1), blk, 0, stream>>>(q_sums, q_cnt, g_cen, g_cntf);
    k3_var<<<dim3(NN / P3, BB), blk, 0, stream>>>(emb, mask, g_cen, q_var);
    k4_final<<<dim3(1), blk, 0, stream>>>(g_cen, g_cntf, q_var, out);
}